// Round 6
// baseline (284.147 us; speedup 1.0000x reference)
//
#include <hip/hip_runtime.h>
#include <math.h>

// Problem constants (from reference): B=8, C=512, L=4096, fp32.
#define C_CH   512
#define TOPK   256               // C * (1 - EXCHANGE_RATIO)
#define NPAIR  (C_CH - TOPK)     // 256 exchanged channel pairs
#define B_N    8
#define L_LEN  4096
#define L4     (L_LEN / 4)       // 1024 float4 per channel row (16 KB)
#define TENSOR_BYTES ((size_t)B_N * C_CH * L_LEN * 4)   // 64 MiB per tensor

// v6: route the bulk copy through the DRIVER's D2D blit (hipMemcpyAsync), which
// is the only proven-fast path in this harness (fillBufferAligned = 6.6 TB/s;
// our best hand-written copy variants all pin at 3.35 TB/s logical regardless of
// structure). Then a small fix-up kernel overwrites only the exchanged half
// (LLC-hot: its sources were just streamed by the memcpy). If the vendor blit
// ALSO runs at ~3.35 TB/s on this data, that's decisive external evidence of the
// platform copy ceiling for this mix.

// build_maps now only emits the two non-top channel lists, ascending index
// order (matches torch/jax boolean-mask semantics): nt1[p] <-> nt2[p] exchange.
__global__ __launch_bounds__(C_CH) void build_maps(
        const float* __restrict__ bn1,
        const float* __restrict__ bn2,
        int* __restrict__ nt1g,
        int* __restrict__ nt2g) {
    __shared__ float2 a12[C_CH];
    __shared__ int wsum1[8], wsum2[8];
    const int t = threadIdx.x;
    const float v1 = fabsf(bn1[t]);
    const float v2 = fabsf(bn2[t]);
    a12[t] = make_float2(v1, v2);
    __syncthreads();

    // Rank among |bn| values (descending, ties by lower index).
    int r1 = 0, r2 = 0;
#pragma unroll 8
    for (int j = 0; j < C_CH; ++j) {
        const float2 bj = a12[j];
        r1 += (bj.x > v1) || (bj.x == v1 && j < t);
        r2 += (bj.y > v2) || (bj.y == v2 && j < t);
    }
    const bool non1 = (r1 >= TOPK);   // non-top channel of bn1
    const bool non2 = (r2 >= TOPK);

    // Ballot-based prefix count -> position in ascending index order.
    const unsigned long long m1 = __ballot(non1);
    const unsigned long long m2 = __ballot(non2);
    const int lane = t & 63, w = t >> 6;
    const unsigned long long below = (1ULL << lane) - 1ULL;
    const int lp1 = __popcll(m1 & below);
    const int lp2 = __popcll(m2 & below);
    if (lane == 0) { wsum1[w] = __popcll(m1); wsum2[w] = __popcll(m2); }
    __syncthreads();
    int base1 = 0, base2 = 0;
#pragma unroll
    for (int i = 0; i < 8; ++i) {
        base1 += (i < w) ? wsum1[i] : 0;
        base2 += (i < w) ? wsum2[i] : 0;
    }
    if (non1) nt1g[base1 + lp1] = t;
    if (non2) nt2g[base2 + lp2] = t;
}

// Fix-up: one block per (b, pair p). Copies the two exchanged rows:
//   y1[b][nt1[p]] = x2[b][nt2[p]]
//   y2[b][nt2[p]] = x1[b][nt1[p]]
// 2048 blocks x 256 threads; per thread 2x4 float4. Loads all issued before
// stores (independent registers). Sources are LLC-hot (just streamed by the
// bulk memcpys); dests are LLC-hot just-written lines.
__global__ __launch_bounds__(256) void exchange_fix(
        const float4* __restrict__ x1,
        const float4* __restrict__ x2,
        const int* __restrict__ nt1,
        const int* __restrict__ nt2,
        float4* __restrict__ y1,
        float4* __restrict__ y2) {
    const int blk = blockIdx.x;          // 0 .. B_N*NPAIR-1
    const int p = blk & (NPAIR - 1);
    const int b = blk >> 8;
    const int c1 = nt1[p];               // uniform -> scalar load
    const int c2 = nt2[p];

    const float4* __restrict__ s1 = x2 + ((size_t)((b << 9) | c2) << 10);
    float4* __restrict__       d1 = y1 + ((size_t)((b << 9) | c1) << 10);
    const float4* __restrict__ s2 = x1 + ((size_t)((b << 9) | c1) << 10);
    float4* __restrict__       d2 = y2 + ((size_t)((b << 9) | c2) << 10);

    const int t = threadIdx.x;
    float4 ra[4], rb[4];
#pragma unroll
    for (int k = 0; k < 4; ++k) ra[k] = s1[t + 256 * k];
#pragma unroll
    for (int k = 0; k < 4; ++k) rb[k] = s2[t + 256 * k];
#pragma unroll
    for (int k = 0; k < 4; ++k) d1[t + 256 * k] = ra[k];
#pragma unroll
    for (int k = 0; k < 4; ++k) d2[t + 256 * k] = rb[k];
}

extern "C" void kernel_launch(void* const* d_in, const int* in_sizes, int n_in,
                              void* d_out, int out_size, void* d_ws, size_t ws_size,
                              hipStream_t stream) {
    const float* x1  = (const float*)d_in[0];
    const float* x2  = (const float*)d_in[1];
    const float* bn1 = (const float*)d_in[2];
    const float* bn2 = (const float*)d_in[3];

    float* y1 = (float*)d_out;                         // first B*C*L floats
    float* y2 = (float*)d_out + (B_N * C_CH * L_LEN);  // second output

    int* nt1 = (int*)d_ws;
    int* nt2 = nt1 + NPAIR;

    // Tiny: computes the exchange lists while the stream is otherwise idle.
    build_maps<<<1, C_CH, 0, stream>>>(bn1, bn2, nt1, nt2);

    // Bulk: vendor blit path. y1 = x1, y2 = x2 wholesale.
    hipMemcpyAsync(y1, x1, TENSOR_BYTES, hipMemcpyDeviceToDevice, stream);
    hipMemcpyAsync(y2, x2, TENSOR_BYTES, hipMemcpyDeviceToDevice, stream);

    // Fix-up: overwrite the exchanged half (64 MiB payload, LLC-hot).
    exchange_fix<<<B_N * NPAIR, 256, 0, stream>>>(
        (const float4*)x1, (const float4*)x2, nt1, nt2,
        (float4*)y1, (float4*)y2);
}